// Round 1
// baseline (423.226 us; speedup 1.0000x reference)
//
#include <hip/hip_runtime.h>

typedef unsigned short u16;
typedef unsigned int u32;
typedef __attribute__((ext_vector_type(4))) float f32x4;
typedef __attribute__((ext_vector_type(8))) short bf16x8;

#define T_DIM 2048
#define E_DIM 1024
#define NBATCH 8
#define TILES_PER_BATCH 136  // 16*17/2 causal 128x128 tiles

struct alignas(8)  U16x4 { u16 x, y, z, w; };
struct alignas(16) F32x4 { float x, y, z, w; };

__device__ __forceinline__ u16 f2bf(float f) {
  u32 u = __float_as_uint(f);
  u += 0x7FFFu + ((u >> 16) & 1u);
  return (u16)(u >> 16);
}

__device__ __forceinline__ float bf2f(u16 h) {
  return __uint_as_float(((u32)h) << 16);
}

__device__ __forceinline__ void gld16(u16* lds, const u16* g) {
  __builtin_amdgcn_global_load_lds((const __attribute__((address_space(1))) void*)g,
                                   (__attribute__((address_space(3))) void*)lds, 16, 0, 0);
}

// C = A * B^T core: A [.,K] row-major bf16, B [.,K] row-major bf16.
// 128x128 tile, BK=32, 256 threads (4 waves, each a 64x64 subtile of 4x4 16x16x32 MFMA frags).
__device__ __forceinline__ void gemm_bt_loop(const u16* __restrict__ A, const u16* __restrict__ B,
                                             int lda, int ldb, int kLen,
                                             u16* sA, u16* sB, f32x4 acc[4][4])
{
  const int t = threadIdx.x;
  const int lane = t & 63;
  const int wave = t >> 6;
  const int wr = wave >> 1, wc = wave & 1;
  const int r0 = t >> 2;            // staging row for load idx = t
  const int kg0 = (t & 3) * 8;      // staging k-offset (elements)
  const int arow = wr * 64 + (lane & 15);
  const int brow = wc * 64 + (lane & 15);
  const int koff = (lane >> 4) * 8;

  for (int k0 = 0; k0 < kLen; k0 += 32) {
    __syncthreads();  // protect LDS from previous iteration's readers
    gld16(&sA[t * 8],         A + (size_t)r0 * lda + (k0 + kg0));
    gld16(&sA[(t + 256) * 8], A + (size_t)(r0 + 64) * lda + (k0 + kg0));
    gld16(&sB[t * 8],         B + (size_t)r0 * ldb + (k0 + kg0));
    gld16(&sB[(t + 256) * 8], B + (size_t)(r0 + 64) * ldb + (k0 + kg0));
    __syncthreads();  // drains vmcnt(0): staged data visible
    bf16x8 af[4], bfv[4];
#pragma unroll
    for (int i = 0; i < 4; i++) af[i]  = *(const bf16x8*)&sA[(arow + i * 16) * 32 + koff];
#pragma unroll
    for (int i = 0; i < 4; i++) bfv[i] = *(const bf16x8*)&sB[(brow + i * 16) * 32 + koff];
#pragma unroll
    for (int m = 0; m < 4; m++)
#pragma unroll
      for (int n = 0; n < 4; n++)
        acc[m][n] = __builtin_amdgcn_mfma_f32_16x16x32_bf16(af[m], bfv[n], acc[m][n], 0, 0, 0);
  }
}

// fp32 -> bf16 convert, 4 elems/thread
__global__ __launch_bounds__(256) void k_cvt(const float* __restrict__ in, u16* __restrict__ out, int n4)
{
  int i = blockIdx.x * 256 + threadIdx.x;
  if (i >= n4) return;
  F32x4 v = *(const F32x4*)&in[(size_t)i * 4];
  U16x4 o;
  o.x = f2bf(v.x); o.y = f2bf(v.y); o.z = f2bf(v.z); o.w = f2bf(v.w);
  *(U16x4*)&out[(size_t)i * 4] = o;
}

// QKV projection: [M=nbc*T, 3E] = Xb[M,E] * Wb[3E,E]^T + bias. Writes Q,K row-major bf16, V transposed.
__global__ __launch_bounds__(256) void k_qkv(const u16* __restrict__ Xb, const u16* __restrict__ Wb,
                                             const float* __restrict__ bias,
                                             u16* __restrict__ Q, u16* __restrict__ Kmat,
                                             u16* __restrict__ Vt)
{
  __shared__ __align__(16) u16 sA[128 * 32];
  __shared__ __align__(16) u16 sB[128 * 32];
  f32x4 acc[4][4] = {};
  const int m0 = blockIdx.y * 128;
  const int n0 = blockIdx.x * 128;
  gemm_bt_loop(Xb + (size_t)m0 * E_DIM, Wb + (size_t)n0 * E_DIM, E_DIM, E_DIM, E_DIM, sA, sB, acc);

  const int t = threadIdx.x, lane = t & 63, wave = t >> 6;
  const int wr = wave >> 1, wc = wave & 1;
  const int region = n0 >> 10;  // 0=q 1=k 2=v (128 | 1024 so uniform per block)
#pragma unroll
  for (int n = 0; n < 4; n++) {
    const int ng = n0 + wc * 64 + n * 16 + (lane & 15);
    const float bn = bias[ng];
    const int nl = ng & (E_DIM - 1);
#pragma unroll
    for (int m = 0; m < 4; m++) {
      const int mg0 = m0 + wr * 64 + m * 16 + (lane >> 4) * 4;
      if (region < 2) {
        u16* dst = region ? Kmat : Q;
#pragma unroll
        for (int r = 0; r < 4; r++)
          dst[(size_t)(mg0 + r) * E_DIM + nl] = f2bf(acc[m][n][r] + bn);
      } else {
        const int bl = mg0 >> 11;            // chunk-local batch (T=2048)
        const int t0 = mg0 & (T_DIM - 1);
        U16x4 pk;
        pk.x = f2bf(acc[m][n][0] + bn);
        pk.y = f2bf(acc[m][n][1] + bn);
        pk.z = f2bf(acc[m][n][2] + bn);
        pk.w = f2bf(acc[m][n][3] + bn);
        *(U16x4*)&Vt[((size_t)bl * E_DIM + nl) * T_DIM + t0] = pk;
      }
    }
  }
}

// Causal score tiles: S = Q*K^T * scale (fp32), masked entries = -1e30
__global__ __launch_bounds__(256) void k_scores(const u16* __restrict__ Q, const u16* __restrict__ Kmat,
                                                float* __restrict__ S)
{
  __shared__ __align__(16) u16 sA[128 * 32];
  __shared__ __align__(16) u16 sB[128 * 32];
  const int b  = blockIdx.x / TILES_PER_BATCH;
  const int ti = blockIdx.x % TILES_PER_BATCH;
  int iq = (int)((sqrtf(8.f * ti + 1.f) - 1.f) * 0.5f);
  while ((iq + 1) * (iq + 2) / 2 <= ti) ++iq;
  while (iq * (iq + 1) / 2 > ti) --iq;
  const int ik = ti - iq * (iq + 1) / 2;

  f32x4 acc[4][4] = {};
  const u16* Qp = Q    + (size_t)b * T_DIM * E_DIM + (size_t)iq * 128 * E_DIM;
  const u16* Kp = Kmat + (size_t)b * T_DIM * E_DIM + (size_t)ik * 128 * E_DIM;
  gemm_bt_loop(Qp, Kp, E_DIM, E_DIM, E_DIM, sA, sB, acc);

  const int t = threadIdx.x, lane = t & 63, wave = t >> 6;
  const int wr = wave >> 1, wc = wave & 1;
  float* Sb = S + (size_t)b * T_DIM * T_DIM;
  const float scale = 0.03125f;  // 1/sqrt(1024)
#pragma unroll
  for (int n = 0; n < 4; n++) {
    const int kg = ik * 128 + wc * 64 + n * 16 + (lane & 15);
#pragma unroll
    for (int m = 0; m < 4; m++) {
#pragma unroll
      for (int r = 0; r < 4; r++) {
        const int qg = iq * 128 + wr * 64 + m * 16 + (lane >> 4) * 4 + r;
        Sb[(size_t)qg * T_DIM + kg] = (kg <= qg) ? acc[m][n][r] * scale : -1e30f;
      }
    }
  }
}

// Row softmax stats: one wave per row. Reads fp32 S, writes bf16 P = exp(s - m), stores 1/sum.
__global__ __launch_bounds__(256) void k_stats(const float* __restrict__ S, u16* __restrict__ P,
                                               float* __restrict__ invl)
{
  const int wave = threadIdx.x >> 6, lane = threadIdx.x & 63;
  const int rg = blockIdx.x * 4 + wave;           // chunk-local row
  const int bl = rg >> 11, q = rg & (T_DIM - 1);
  const float* row = S + (size_t)bl * T_DIM * T_DIM + (size_t)q * T_DIM;
  u16* prow       = P + (size_t)bl * T_DIM * T_DIM + (size_t)q * T_DIM;
  const int Cend = ((q >> 7) + 1) << 7;           // written (causal+diag-masked) prefix

  float m = -3.4e38f;
  for (int c = lane * 4; c < Cend; c += 256) {
    F32x4 v = *(const F32x4*)&row[c];
    m = fmaxf(m, fmaxf(fmaxf(v.x, v.y), fmaxf(v.z, v.w)));
  }
#pragma unroll
  for (int off = 32; off; off >>= 1) m = fmaxf(m, __shfl_xor(m, off, 64));

  float l = 0.f;
  for (int c = lane * 4; c < Cend; c += 256) {
    F32x4 v = *(const F32x4*)&row[c];
    float e0 = __expf(v.x - m), e1 = __expf(v.y - m), e2 = __expf(v.z - m), e3 = __expf(v.w - m);
    l += e0 + e1 + e2 + e3;
    U16x4 pk; pk.x = f2bf(e0); pk.y = f2bf(e1); pk.z = f2bf(e2); pk.w = f2bf(e3);
    *(U16x4*)&prow[c] = pk;
  }
#pragma unroll
  for (int off = 32; off; off >>= 1) l += __shfl_xor(l, off, 64);
  if (lane == 0) invl[rg] = 1.f / l;
}

// PV: Y[q,e] = (1/l_q) * sum_k P[q,k] * Vt[e,k] over causal k-tiles. fp32 out.
__global__ __launch_bounds__(256) void k_pv(const u16* __restrict__ P, const u16* __restrict__ Vt,
                                            const float* __restrict__ invl, float* __restrict__ out,
                                            int batch0)
{
  __shared__ __align__(16) u16 sA[128 * 32];
  __shared__ __align__(16) u16 sB[128 * 32];
  const int bl = blockIdx.y >> 4, iq = blockIdx.y & 15;
  const int ie = blockIdx.x;
  f32x4 acc[4][4] = {};
  const u16* Ap = P  + (size_t)bl * T_DIM * T_DIM + (size_t)iq * 128 * T_DIM;
  const u16* Bp = Vt + (size_t)bl * E_DIM * T_DIM + (size_t)ie * 128 * T_DIM;
  gemm_bt_loop(Ap, Bp, T_DIM, T_DIM, (iq + 1) * 128, sA, sB, acc);

  const int t = threadIdx.x, lane = t & 63, wave = t >> 6;
  const int wr = wave >> 1, wc = wave & 1;
#pragma unroll
  for (int m = 0; m < 4; m++) {
#pragma unroll
    for (int r = 0; r < 4; r++) {
      const int qg = iq * 128 + wr * 64 + m * 16 + (lane >> 4) * 4 + r;
      const float il = invl[bl * T_DIM + qg];
      float* orow = out + ((size_t)(batch0 + bl) * T_DIM + qg) * E_DIM;
#pragma unroll
      for (int n = 0; n < 4; n++) {
        const int eg = ie * 128 + wc * 64 + n * 16 + (lane & 15);
        orow[eg] = acc[m][n][r] * il;
      }
    }
  }
}

extern "C" void kernel_launch(void* const* d_in, const int* in_sizes, int n_in,
                              void* d_out, int out_size, void* d_ws, size_t ws_size,
                              hipStream_t stream)
{
  const float* x    = (const float*)d_in[0];  // [8, 2048, 1024]
  const float* W    = (const float*)d_in[1];  // [3072, 1024]
  const float* bias = (const float*)d_in[2];  // [3072]
  float* out = (float*)d_out;

  char* ws = (char*)d_ws;
  const size_t ALIGN = 256;
  auto up = [&](size_t v) { return (v + ALIGN - 1) & ~(ALIGN - 1); };

  const size_t szWb = up((size_t)3 * E_DIM * E_DIM * 2);
  const size_t szX  = up((size_t)T_DIM * E_DIM * 2);       // per-batch bf16 [T,E]
  const size_t szS  = up((size_t)T_DIM * T_DIM * 4);       // per-batch fp32 scores
  const size_t szP  = up((size_t)T_DIM * T_DIM * 2);       // per-batch bf16 probs
  const size_t szI  = up((size_t)T_DIM * 4);               // per-batch 1/l
  const size_t perB = 4 * szX + szS + szP + szI;           // X,Q,K,Vt + S + P + invl

  int nb = 1;
  for (int cand = NBATCH; cand >= 1; --cand) {
    if (szWb + (size_t)cand * perB <= ws_size) { nb = cand; break; }
  }

  u16* Wb = (u16*)ws;

  // Convert W once
  {
    int n4 = 3 * E_DIM * E_DIM / 4;
    k_cvt<<<(n4 + 255) / 256, 256, 0, stream>>>(W, Wb, n4);
  }

  for (int b0 = 0; b0 < NBATCH; b0 += nb) {
    const int nbc = (NBATCH - b0 < nb) ? (NBATCH - b0) : nb;
    size_t o = szWb;
    u16* Xb    = (u16*)(ws + o);  o += (size_t)nbc * szX;
    u16* Qb    = (u16*)(ws + o);  o += (size_t)nbc * szX;
    u16* Kb    = (u16*)(ws + o);  o += (size_t)nbc * szX;
    u16* Vt    = (u16*)(ws + o);  o += (size_t)nbc * szX;
    float* S   = (float*)(ws + o); o += (size_t)nbc * szS;
    u16* P     = (u16*)(ws + o);  o += (size_t)nbc * szP;
    float* inv = (float*)(ws + o); o += (size_t)nbc * szI;

    // x chunk -> bf16
    {
      int n4 = nbc * T_DIM * E_DIM / 4;
      k_cvt<<<(n4 + 255) / 256, 256, 0, stream>>>(x + (size_t)b0 * T_DIM * E_DIM, Xb, n4);
    }
    // QKV projection
    {
      dim3 g(3 * E_DIM / 128, nbc * T_DIM / 128);
      k_qkv<<<g, 256, 0, stream>>>(Xb, Wb, bias, Qb, Kb, Vt);
    }
    // causal score tiles
    k_scores<<<nbc * TILES_PER_BATCH, 256, 0, stream>>>(Qb, Kb, S);
    // softmax stats + P
    k_stats<<<nbc * (T_DIM / 4), 256, 0, stream>>>(S, P, inv);
    // PV
    {
      dim3 g(E_DIM / 128, nbc * 16);
      k_pv<<<g, 256, 0, stream>>>(P, Vt, inv, out, b0);
    }
  }
}

// Round 2
// 390.461 us; speedup vs baseline: 1.0839x; 1.0839x over previous
//
#include <hip/hip_runtime.h>

typedef unsigned short u16;
typedef unsigned int u32;
typedef __attribute__((ext_vector_type(4))) float f32x4;
typedef __attribute__((ext_vector_type(8))) short bf16x8;

#define T_DIM 2048
#define E_DIM 1024
#define NBATCH 8
#define BK 32
#define BUF_BYTES 32768  // 16KB A + 16KB B per K-tile buffer

struct alignas(8)  U16x4 { u16 x, y, z, w; };
struct alignas(16) F32x4 { float x, y, z, w; };

__device__ __forceinline__ u16 f2bf(float f) {
  u32 u = __float_as_uint(f);
  u += 0x7FFFu + ((u >> 16) & 1u);
  return (u16)(u >> 16);
}

__device__ __forceinline__ void gld16(u16* lds, const u16* g) {
  __builtin_amdgcn_global_load_lds((const __attribute__((address_space(1))) void*)g,
                                   (__attribute__((address_space(3))) void*)lds, 16, 0, 0);
}

// LDS bank swizzle: flip byte bits 4,5 with bits 8,9 (involution, 16B-chunk-uniform).
__device__ __forceinline__ u32 swz(u32 x) { return x ^ ((x >> 4) & 0x30u); }

// Bijective XCD-aware block remap (m204 form).
__device__ __forceinline__ int xcd_swz(int orig, int nwg) {
  int q = nwg >> 3, r = nwg & 7;
  int x = orig & 7, l = orig >> 3;
  return (x < r ? x * (q + 1) : r * (q + 1) + (x - r) * q) + l;
}

// Stage K-tile tt (A: 256 x 32, B: 256 x 32 bf16) into buffer tt&3.
// Linear LDS dest for global_load_lds; source address pre-swizzled so that
// swizzled reads see row-major data.
__device__ __forceinline__ void stage256(u16* ldsb, const u16* __restrict__ A,
                                         const u16* __restrict__ B, int lda, int ldb, int tt)
{
  char* dst = (char*)ldsb + (size_t)(tt & 3) * BUF_BYTES;
  const u16* Ak = A + tt * BK;
  const u16* Bk = B + tt * BK;
  const int tid = threadIdx.x;
#pragma unroll
  for (int h = 0; h < 2; ++h) {
    u32 lin = (u32)(h * 8192 + tid * 16);
    u32 sw = swz(lin);
    u32 row = sw >> 6;            // 64B per row (BK=32 bf16)
    u32 ce = (sw & 63u) >> 1;     // element offset in row
    gld16((u16*)(dst + lin),         Ak + (size_t)row * lda + ce);
    gld16((u16*)(dst + 16384 + lin), Bk + (size_t)row * ldb + ce);
  }
}

// One K-tile of MFMA work for this wave: 8 m-frags x 4 n-frags, K=32.
__device__ __forceinline__ void compute256(const u16* ldsb, int t, int wr, int wc, int lane,
                                           f32x4 acc[8][4])
{
  const char* bufA = (const char*)ldsb + (size_t)(t & 3) * BUF_BYTES;
  const char* bufB = bufA + 16384;
  const u32 kb = (u32)((lane >> 4) * 16);
  bf16x8 a[8], b[4];
#pragma unroll
  for (int m = 0; m < 8; ++m) {
    u32 x = (u32)(wr * 128 + m * 16 + (lane & 15)) * 64 + kb;
    a[m] = *(const bf16x8*)(bufA + swz(x));
  }
#pragma unroll
  for (int n = 0; n < 4; ++n) {
    u32 x = (u32)(wc * 64 + n * 16 + (lane & 15)) * 64 + kb;
    b[n] = *(const bf16x8*)(bufB + swz(x));
  }
  __builtin_amdgcn_s_setprio(1);
#pragma unroll
  for (int m = 0; m < 8; ++m)
#pragma unroll
    for (int n = 0; n < 4; ++n)
      acc[m][n] = __builtin_amdgcn_mfma_f32_16x16x32_bf16(a[m], b[n], acc[m][n], 0, 0, 0);
  __builtin_amdgcn_s_setprio(0);
}

// C = A * B^T, 256x256 tile, 512 threads (8 waves = 2M x 4N), BK=32,
// 4 LDS buffers, 3-deep prefetch, counted vmcnt (never 0 in main loop).
// Requires nK >= 3.
__device__ __forceinline__ void gemm256(const u16* __restrict__ A, const u16* __restrict__ B,
                                        int lda, int ldb, int nK, u16* ldsb,
                                        int wr, int wc, int lane, f32x4 acc[8][4])
{
  stage256(ldsb, A, B, lda, ldb, 0);
  stage256(ldsb, A, B, lda, ldb, 1);
  stage256(ldsb, A, B, lda, ldb, 2);
  int t = 0;
  for (; t < nK - 2; ++t) {
    // own loads for tile t retired (12 -> 8 outstanding); barrier -> all waves' visible
    asm volatile("s_waitcnt vmcnt(8)\n\ts_barrier" ::: "memory");
    if (t + 3 < nK) stage256(ldsb, A, B, lda, ldb, t + 3);
    compute256(ldsb, t, wr, wc, lane, acc);
  }
  asm volatile("s_waitcnt vmcnt(4)\n\ts_barrier" ::: "memory");
  compute256(ldsb, t, wr, wc, lane, acc);
  ++t;
  asm volatile("s_waitcnt vmcnt(0)\n\ts_barrier" ::: "memory");
  compute256(ldsb, t, wr, wc, lane, acc);
}

// fp32 -> bf16 convert, 4 elems/thread
__global__ __launch_bounds__(256) void k_cvt(const float* __restrict__ in, u16* __restrict__ out, int n4)
{
  int i = blockIdx.x * 256 + threadIdx.x;
  if (i >= n4) return;
  F32x4 v = *(const F32x4*)&in[(size_t)i * 4];
  U16x4 o;
  o.x = f2bf(v.x); o.y = f2bf(v.y); o.z = f2bf(v.z); o.w = f2bf(v.w);
  *(U16x4*)&out[(size_t)i * 4] = o;
}

// QKV projection: [M=nbc*T, 3E] = Xb * Wb^T + bias. Q,K row-major bf16; V transposed.
__global__ __launch_bounds__(512, 2) void k_qkv(const u16* __restrict__ Xb, const u16* __restrict__ Wb,
                                                const float* __restrict__ bias,
                                                u16* __restrict__ Q, u16* __restrict__ Kmat,
                                                u16* __restrict__ Vt)
{
  __shared__ __align__(16) u16 lds[4 * BUF_BYTES / 2];
  const int wg = xcd_swz(blockIdx.x, gridDim.x);
  const int my = wg / 12, nx = wg % 12;
  const int m0 = my * 256, n0 = nx * 256;
  const int tid = threadIdx.x, lane = tid & 63, wave = tid >> 6;
  const int wr = wave >> 2, wc = wave & 3;
  f32x4 acc[8][4] = {};
  gemm256(Xb + (size_t)m0 * E_DIM, Wb + (size_t)n0 * E_DIM, E_DIM, E_DIM, E_DIM / BK,
          lds, wr, wc, lane, acc);

  const int region = nx >> 2;  // 0=Q 1=K 2=V (uniform per block)
#pragma unroll
  for (int n = 0; n < 4; ++n) {
    const int ng = n0 + wc * 64 + n * 16 + (lane & 15);
    const float bn = bias[ng];
    const int nl = ng & (E_DIM - 1);
#pragma unroll
    for (int m = 0; m < 8; ++m) {
      const int mg0 = m0 + wr * 128 + m * 16 + ((lane >> 4) << 2);
      if (region < 2) {
        u16* dst = region ? Kmat : Q;
#pragma unroll
        for (int r = 0; r < 4; ++r)
          dst[(size_t)(mg0 + r) * E_DIM + nl] = f2bf(acc[m][n][r] + bn);
      } else {
        const int bl = mg0 >> 11;            // chunk-local batch
        const int t0 = mg0 & (T_DIM - 1);
        U16x4 pk;
        pk.x = f2bf(acc[m][n][0] + bn);
        pk.y = f2bf(acc[m][n][1] + bn);
        pk.z = f2bf(acc[m][n][2] + bn);
        pk.w = f2bf(acc[m][n][3] + bn);
        *(U16x4*)&Vt[((size_t)bl * E_DIM + nl) * T_DIM + t0] = pk;
      }
    }
  }
}

// Causal score tiles (256x256): S = Q*K^T * scale (fp32), masked = -1e30
__global__ __launch_bounds__(512, 2) void k_scores(const u16* __restrict__ Q, const u16* __restrict__ Kmat,
                                                   float* __restrict__ S)
{
  __shared__ __align__(16) u16 lds[4 * BUF_BYTES / 2];
  const int wg = xcd_swz(blockIdx.x, gridDim.x);
  const int b = wg / 36;
  const int ti = wg % 36;
  int iq = 0;
  while ((iq + 1) * (iq + 2) / 2 <= ti) ++iq;
  const int ik = ti - iq * (iq + 1) / 2;
  const int tid = threadIdx.x, lane = tid & 63, wave = tid >> 6;
  const int wr = wave >> 2, wc = wave & 3;
  f32x4 acc[8][4] = {};
  const u16* Qp = Q    + (size_t)b * T_DIM * E_DIM + (size_t)iq * 256 * E_DIM;
  const u16* Kp = Kmat + (size_t)b * T_DIM * E_DIM + (size_t)ik * 256 * E_DIM;
  gemm256(Qp, Kp, E_DIM, E_DIM, E_DIM / BK, lds, wr, wc, lane, acc);

  float* Sb = S + (size_t)b * T_DIM * T_DIM;
  const float scale = 0.03125f;  // 1/sqrt(1024)
#pragma unroll
  for (int n = 0; n < 4; ++n) {
    const int kg = ik * 256 + wc * 64 + n * 16 + (lane & 15);
#pragma unroll
    for (int m = 0; m < 8; ++m) {
      const int qg0 = iq * 256 + wr * 128 + m * 16 + ((lane >> 4) << 2);
#pragma unroll
      for (int r = 0; r < 4; ++r) {
        const int qg = qg0 + r;
        Sb[(size_t)qg * T_DIM + kg] = (kg <= qg) ? acc[m][n][r] * scale : -1e30f;
      }
    }
  }
}

// Row softmax stats: one wave per row. Reads fp32 S prefix (256-tile granular),
// writes bf16 P = exp(s - m) (0 where masked), stores 1/sum.
__global__ __launch_bounds__(256) void k_stats(const float* __restrict__ S, u16* __restrict__ P,
                                               float* __restrict__ invl)
{
  const int wave = threadIdx.x >> 6, lane = threadIdx.x & 63;
  const int rg = blockIdx.x * 4 + wave;           // chunk-local row
  const int bl = rg >> 11, q = rg & (T_DIM - 1);
  const float* row = S + (size_t)bl * T_DIM * T_DIM + (size_t)q * T_DIM;
  u16* prow       = P + (size_t)bl * T_DIM * T_DIM + (size_t)q * T_DIM;
  const int Cend = ((q >> 8) + 1) << 8;           // written 256-tile prefix

  float m = -3.4e38f;
  for (int c = lane * 4; c < Cend; c += 256) {
    F32x4 v = *(const F32x4*)&row[c];
    m = fmaxf(m, fmaxf(fmaxf(v.x, v.y), fmaxf(v.z, v.w)));
  }
#pragma unroll
  for (int off = 32; off; off >>= 1) m = fmaxf(m, __shfl_xor(m, off, 64));

  float l = 0.f;
  for (int c = lane * 4; c < Cend; c += 256) {
    F32x4 v = *(const F32x4*)&row[c];
    float e0 = __expf(v.x - m), e1 = __expf(v.y - m), e2 = __expf(v.z - m), e3 = __expf(v.w - m);
    l += e0 + e1 + e2 + e3;
    U16x4 pk; pk.x = f2bf(e0); pk.y = f2bf(e1); pk.z = f2bf(e2); pk.w = f2bf(e3);
    *(U16x4*)&prow[c] = pk;
  }
#pragma unroll
  for (int off = 32; off; off >>= 1) l += __shfl_xor(l, off, 64);
  if (lane == 0) invl[rg] = 1.f / l;
}

// PV: Y[q,e] = (1/l_q) * sum_k P[q,k] * Vt[e,k] over causal k prefix. fp32 out.
__global__ __launch_bounds__(512, 2) void k_pv(const u16* __restrict__ P, const u16* __restrict__ Vt,
                                               const float* __restrict__ invl, float* __restrict__ out,
                                               int batch0)
{
  __shared__ __align__(16) u16 lds[4 * BUF_BYTES / 2];
  const int wg = xcd_swz(blockIdx.x, gridDim.x);
  const int bl = wg >> 5, rr = wg & 31;
  const int iq = rr >> 2, ie = rr & 3;
  const int tid = threadIdx.x, lane = tid & 63, wave = tid >> 6;
  const int wr = wave >> 2, wc = wave & 3;
  f32x4 acc[8][4] = {};
  const u16* Ap = P  + (size_t)bl * T_DIM * T_DIM + (size_t)iq * 256 * T_DIM;
  const u16* Bp = Vt + (size_t)bl * E_DIM * T_DIM + (size_t)ie * 256 * T_DIM;
  gemm256(Ap, Bp, T_DIM, T_DIM, (iq + 1) * 8, lds, wr, wc, lane, acc);

#pragma unroll
  for (int m = 0; m < 8; ++m) {
    const int qg0 = iq * 256 + wr * 128 + m * 16 + ((lane >> 4) << 2);
#pragma unroll
    for (int r = 0; r < 4; ++r) {
      const int qg = qg0 + r;
      const float il = invl[bl * T_DIM + qg];
      float* orow = out + ((size_t)(batch0 + bl) * T_DIM + qg) * E_DIM;
#pragma unroll
      for (int n = 0; n < 4; ++n) {
        const int eg = ie * 256 + wc * 64 + n * 16 + (lane & 15);
        orow[eg] = acc[m][n][r] * il;
      }
    }
  }
}

extern "C" void kernel_launch(void* const* d_in, const int* in_sizes, int n_in,
                              void* d_out, int out_size, void* d_ws, size_t ws_size,
                              hipStream_t stream)
{
  const float* x    = (const float*)d_in[0];  // [8, 2048, 1024]
  const float* W    = (const float*)d_in[1];  // [3072, 1024]
  const float* bias = (const float*)d_in[2];  // [3072]
  float* out = (float*)d_out;

  char* ws = (char*)d_ws;
  const size_t ALIGN = 256;
  auto up = [&](size_t v) { return (v + ALIGN - 1) & ~(ALIGN - 1); };

  const size_t szWb = up((size_t)3 * E_DIM * E_DIM * 2);
  const size_t szX  = up((size_t)T_DIM * E_DIM * 2);       // per-batch bf16 [T,E]
  const size_t szS  = up((size_t)T_DIM * T_DIM * 4);       // per-batch fp32 scores
  const size_t szP  = up((size_t)T_DIM * T_DIM * 2);       // per-batch bf16 probs
  const size_t szI  = up((size_t)T_DIM * 4);               // per-batch 1/l
  const size_t perB = 4 * szX + szS + szP + szI;

  int nb = 1;
  for (int cand = NBATCH; cand >= 1; --cand) {
    if (szWb + (size_t)cand * perB <= ws_size) { nb = cand; break; }
  }

  u16* Wb = (u16*)ws;
  {
    int n4 = 3 * E_DIM * E_DIM / 4;
    k_cvt<<<(n4 + 255) / 256, 256, 0, stream>>>(W, Wb, n4);
  }

  for (int b0 = 0; b0 < NBATCH; b0 += nb) {
    const int nbc = (NBATCH - b0 < nb) ? (NBATCH - b0) : nb;
    size_t o = szWb;
    u16* Xb    = (u16*)(ws + o);  o += (size_t)nbc * szX;
    u16* Qb    = (u16*)(ws + o);  o += (size_t)nbc * szX;
    u16* Kb    = (u16*)(ws + o);  o += (size_t)nbc * szX;
    u16* Vt    = (u16*)(ws + o);  o += (size_t)nbc * szX;
    float* S   = (float*)(ws + o); o += (size_t)nbc * szS;
    u16* P     = (u16*)(ws + o);  o += (size_t)nbc * szP;
    float* inv = (float*)(ws + o); o += (size_t)nbc * szI;

    {
      int n4 = nbc * T_DIM * E_DIM / 4;
      k_cvt<<<(n4 + 255) / 256, 256, 0, stream>>>(x + (size_t)b0 * T_DIM * E_DIM, Xb, n4);
    }
    k_qkv<<<dim3(96 * nbc), 512, 0, stream>>>(Xb, Wb, bias, Qb, Kb, Vt);
    k_scores<<<dim3(36 * nbc), 512, 0, stream>>>(Qb, Kb, S);
    k_stats<<<nbc * (T_DIM / 4), 256, 0, stream>>>(S, P, inv);
    k_pv<<<dim3(32 * nbc), 512, 0, stream>>>(P, Vt, inv, out, b0);
  }
}